// Round 2
// baseline (528.528 us; speedup 1.0000x reference)
//
#include <hip/hip_runtime.h>
#include <hip/hip_bf16.h>
#include <cmath>

typedef unsigned short u16;
typedef short short8 __attribute__((ext_vector_type(8)));   // 8 bf16 (4 VGPRs)
typedef float f32x4 __attribute__((ext_vector_type(4)));    // 4 fp32 acc

#define D_ 768
#define NTOK 16384      // B * N = 16 * 1024
#define INNER_ 192
#define HID_ 3072

__device__ __forceinline__ float u2f(u16 u) { return __uint_as_float((unsigned)u << 16); }
__device__ __forceinline__ u16 f2u(float f) {
  __hip_bfloat16 h = __float2bfloat16(f);
  u16 u; __builtin_memcpy(&u, &h, 2); return u;
}
// Flag-aware scalar load/store: harness tensors are f32 (flag=1) or bf16 (0).
__device__ __forceinline__ float ld1(const void* p, size_t i, int f32) {
  return f32 ? ((const float*)p)[i] : u2f(((const u16*)p)[i]);
}
__device__ __forceinline__ void st1(void* p, size_t i, float v, int f32) {
  if (f32) ((float*)p)[i] = v; else ((u16*)p)[i] = f2u(v);
}
__device__ __forceinline__ float gelu_exact(float v) {
  return 0.5f * v * (1.f + erff(v * 0.7071067811865476f));
}
// Unpack 8 bf16 (uint4) -> 8 f32.
__device__ __forceinline__ void unpack8(const uint4 v, float* o) {
  o[0] = u2f((u16)(v.x & 0xffffu)); o[1] = u2f((u16)(v.x >> 16));
  o[2] = u2f((u16)(v.y & 0xffffu)); o[3] = u2f((u16)(v.y >> 16));
  o[4] = u2f((u16)(v.z & 0xffffu)); o[5] = u2f((u16)(v.z >> 16));
  o[6] = u2f((u16)(v.w & 0xffffu)); o[7] = u2f((u16)(v.w >> 16));
}

// ---------------------------------------------------------------------------
// Dtype detector (verified round 4/5): flag 1 = f32 inputs, 0 = bf16 inputs.
// ---------------------------------------------------------------------------
__global__ __launch_bounds__(64) void detect_kernel(const unsigned* __restrict__ x,
                                                    int* __restrict__ flag) {
  int cnt = 0;
  for (int i = threadIdx.x; i < 512; i += 64) {
    const unsigned e0 = (x[i] >> 7) & 0xFFu;
    if (e0 >= 96u && e0 <= 144u) cnt++;
  }
#pragma unroll
  for (int o = 32; o > 0; o >>= 1) cnt += __shfl_down(cnt, o);
  if (threadIdx.x == 0) flag[0] = (cnt < 256) ? 1 : 0;
}

// ---------------------------------------------------------------------------
// Weight conversion to internal bf16 (10 jobs; grid.y = job id).
// ---------------------------------------------------------------------------
struct CvtJob { const void* src; u16* dst; int n4; };  // n4 = elems/4
struct CvtArgs { CvtJob j[10]; };

__global__ __launch_bounds__(256) void cvt_kernel(CvtArgs a, const int* __restrict__ flagp) {
  const int f32 = flagp[0];
  const CvtJob jb = a.j[blockIdx.y];
  const int i = blockIdx.x * 256 + threadIdx.x;
  if (i >= jb.n4) return;
  if (f32) {
    const float4 v = ((const float4*)jb.src)[i];
    const unsigned lo = (unsigned)f2u(v.x) | ((unsigned)f2u(v.y) << 16);
    const unsigned hi = (unsigned)f2u(v.z) | ((unsigned)f2u(v.w) << 16);
    ((uint2*)jb.dst)[i] = make_uint2(lo, hi);
  } else {
    ((uint2*)jb.dst)[i] = ((const uint2*)jb.src)[i];
  }
}

// ---------------------------------------------------------------------------
// Fused LayerNorm: stats + normalize, one block (256 thr) per token.
// ---------------------------------------------------------------------------
__global__ __launch_bounds__(256) void ln_kernel(const void* __restrict__ x,
                                                 const void* __restrict__ w,
                                                 const void* __restrict__ b,
                                                 u16* __restrict__ y,
                                                 const int* __restrict__ flagp) {
  const int fl = flagp[0];
  const size_t t = blockIdx.x;
  float v[3];
  float s = 0.f, s2 = 0.f;
#pragma unroll
  for (int i = 0; i < 3; i++) {
    v[i] = ld1(x, t * D_ + threadIdx.x + 256 * i, fl);
    s += v[i];
    s2 += v[i] * v[i];
  }
#pragma unroll
  for (int o = 32; o > 0; o >>= 1) {
    s += __shfl_down(s, o);
    s2 += __shfl_down(s2, o);
  }
  __shared__ float ps[4], ps2[4];
  __shared__ float smu, srstd;
  const int wid = threadIdx.x >> 6, lane = threadIdx.x & 63;
  if (lane == 0) { ps[wid] = s; ps2[wid] = s2; }
  __syncthreads();
  if (threadIdx.x == 0) {
    const float a = ps[0] + ps[1] + ps[2] + ps[3];
    const float a2 = ps2[0] + ps2[1] + ps2[2] + ps2[3];
    const float mu = a * (1.f / D_);
    smu = mu;
    srstd = rsqrtf(a2 * (1.f / D_) - mu * mu + 1e-5f);
  }
  __syncthreads();
  const float mu = smu, rstd = srstd;
#pragma unroll
  for (int i = 0; i < 3; i++) {
    const int c = threadIdx.x + 256 * i;
    y[t * D_ + c] = f2u((v[i] - mu) * rstd * ld1(w, c, fl) + ld1(b, c, fl));
  }
}

// ---------------------------------------------------------------------------
// MFMA GEMM (m97 structure, 128x128): kept for fv (N=384) and proj (K=192).
// ---------------------------------------------------------------------------
template <int EPI>
__global__ __launch_bounds__(256) void mfma_gemm(const u16* __restrict__ A, int lda,
                                                 const u16* __restrict__ B, int ldb,
                                                 const u16* __restrict__ bias,
                                                 const void* __restrict__ res,
                                                 void* __restrict__ C, int ldc,
                                                 int K, int row0,
                                                 const int* __restrict__ flagp) {
  const int fl = flagp[0];
  __shared__ __align__(16) u16 Asb[128 * 32];
  __shared__ __align__(16) u16 Bsb[128 * 32];
  const int tid = threadIdx.x;
  const int lane = tid & 63;
  const int wv = tid >> 6;
  const int bm = blockIdx.x * 128;
  const int bn = blockIdx.y * 128;
  const int wm = (wv & 1) * 64;
  const int wn = (wv >> 1) * 64;
  const int c0 = tid, c1 = tid + 256;
  const u16* Ag0 = A + (size_t)(bm + (c0 >> 2)) * lda + (c0 & 3) * 8;
  const u16* Ag1 = A + (size_t)(bm + (c1 >> 2)) * lda + (c1 & 3) * 8;
  const u16* Bg0 = B + (size_t)(bn + (c0 >> 2)) * ldb + (c0 & 3) * 8;
  const u16* Bg1 = B + (size_t)(bn + (c1 >> 2)) * ldb + (c1 & 3) * 8;
  u16* la0 = &Asb[c0 * 8];
  u16* la1 = &Asb[c1 * 8];
  u16* lb0 = &Bsb[c0 * 8];
  u16* lb1 = &Bsb[c1 * 8];

  f32x4 acc[4][4];
#pragma unroll
  for (int i = 0; i < 4; i++)
#pragma unroll
    for (int j = 0; j < 4; j++) acc[i][j] = (f32x4){0.f, 0.f, 0.f, 0.f};

  const int ml = lane & 15;
  const int kq = (lane >> 4) * 8;

  for (int k0 = 0; k0 < K; k0 += 32) {
    __syncthreads();
    __builtin_amdgcn_global_load_lds(
        (const __attribute__((address_space(1))) void*)(Ag0 + k0),
        (__attribute__((address_space(3))) void*)la0, 16, 0, 0);
    __builtin_amdgcn_global_load_lds(
        (const __attribute__((address_space(1))) void*)(Ag1 + k0),
        (__attribute__((address_space(3))) void*)la1, 16, 0, 0);
    __builtin_amdgcn_global_load_lds(
        (const __attribute__((address_space(1))) void*)(Bg0 + k0),
        (__attribute__((address_space(3))) void*)lb0, 16, 0, 0);
    __builtin_amdgcn_global_load_lds(
        (const __attribute__((address_space(1))) void*)(Bg1 + k0),
        (__attribute__((address_space(3))) void*)lb1, 16, 0, 0);
    __syncthreads();
    short8 af[4], bf[4];
#pragma unroll
    for (int i = 0; i < 4; i++) {
      af[i] = *(const short8*)&Asb[(wm + i * 16 + ml) * 32 + kq];
      bf[i] = *(const short8*)&Bsb[(wn + i * 16 + ml) * 32 + kq];
    }
#pragma unroll
    for (int i = 0; i < 4; i++)
#pragma unroll
      for (int j = 0; j < 4; j++)
        acc[i][j] = __builtin_amdgcn_mfma_f32_16x16x32_bf16(af[i], bf[j], acc[i][j], 0, 0, 0);
  }

  const int qr = (lane >> 4) * 4;
#pragma unroll
  for (int i = 0; i < 4; i++) {
#pragma unroll
    for (int j = 0; j < 4; j++) {
      const int colg = bn + wn + j * 16 + ml;
      const float bb = u2f(bias[colg]);
#pragma unroll
      for (int r = 0; r < 4; r++) {
        const size_t row = (size_t)row0 + bm + wm + i * 16 + qr + r;
        float v = acc[i][j][r] + bb;
        if (EPI == 1) v = gelu_exact(v);
        if (EPI == 2) {
          v += ld1(res, row * ldc + colg, fl);
          st1(C, row * ldc + colg, v, fl);
        } else {
          ((u16*)C)[row * ldc + colg] = f2u(v);
        }
      }
    }
  }
}

// ---------------------------------------------------------------------------
// 8-phase 256x256 MFMA GEMM (T2+T3+T4+T5 per the 8-phase template).
// 512 threads = 8 waves (2M x 4N); per-wave output 128x64 (acc[8][4]).
// K-tile BK=64 split into ks0/ks1 slices; LDS regions [buf][A/B][ks] each
// 256x32 bf16 (16 KB), 128 KiB total, double-buffered.
// Swizzle (both-sides, rule 21): 16B chunk q of row goes to slot
// q ^ ((row>>1)&3): linear LDS dest for global_load_lds with pre-swizzled
// global source; ds_read applies the same XOR. 16 lanes -> 8 distinct 16B
// slots (2-way, free).
// Schedule per tile t (buf = t&1), phases j=0..3:
//  j0: read B-ks0 + A-ks0(frags0-3); stage A-ks1 of t+1 (other buf)
//  j1: read A-ks0(frags4-7);        stage B-ks0 of t+2 (this buf; B-ks0
//                                   last read at j0, barrier in between)
//  j2: read B-ks1 + A-ks1(0-3);     stage A-ks0 of t+2 (last read j1)
//  j3: read A-ks1(4-7);             stage B-ks1 of t+2 (last read j2);
//      vmcnt(6) (3 half-tiles in flight) or vmcnt(0) at the end.
// Each phase: {ds_read; stage; barrier; lgkmcnt(0)+sched_barrier;
//              setprio(1); 16 MFMA; setprio(0); barrier}.
// K order of accumulation identical to the 128x128 kernel (bit-identical).
// Requires M%256==0, N%256==0, K%64==0, K>=128.
// ---------------------------------------------------------------------------
#define SB8 __builtin_amdgcn_sched_barrier(0)
#define BAR8 __builtin_amdgcn_s_barrier()

template <int EPI>
__global__ __launch_bounds__(512) void mfma_gemm8(const u16* __restrict__ A, int lda,
                                                  const u16* __restrict__ B, int ldb,
                                                  const u16* __restrict__ bias,
                                                  const void* __restrict__ res,
                                                  void* __restrict__ C, int ldc,
                                                  int K, int row0,
                                                  const int* __restrict__ flagp) {
  const int fl = flagp[0];
  __shared__ __align__(16) u16 L[2][2][2][8192];  // [buf][A=0/B=1][ks][256*32]
  const int tid = threadIdx.x;
  const int lane = tid & 63;
  const int wv = tid >> 6;
  const int bm = blockIdx.x * 256;
  const int bn = blockIdx.y * 256;
  const int wm = (wv >> 2) * 128;   // 0 or 128
  const int wn = (wv & 3) * 64;
  const int ml = lane & 15;
  const int qk = lane >> 4;         // 16B chunk within k-slice

  // Staging geometry: thread covers region chunks c = tid and tid+512;
  // row = c>>2, slot = c&3, global chunk q = slot ^ ((row>>1)&3).
  const int srow = tid >> 2;                      // 0..127
  const int q_s = (tid & 3) ^ ((srow >> 1) & 3);  // same for row and row+128
  const size_t ga0 = (size_t)(bm + srow) * lda + q_s * 8;
  const size_t ga1 = (size_t)(bm + srow + 128) * lda + q_s * 8;
  const size_t gb0 = (size_t)(bn + srow) * ldb + q_s * 8;
  const size_t gb1 = (size_t)(bn + srow + 128) * ldb + q_s * 8;

  // LDS read offsets (elems within a 256x32 region), swizzled.
  int offA[8], offB[4];
#pragma unroll
  for (int i = 0; i < 8; i++) {
    const int r = wm + i * 16 + ml;
    offA[i] = (r * 4 + (qk ^ ((r >> 1) & 3))) * 8;
  }
#pragma unroll
  for (int j = 0; j < 4; j++) {
    const int r = wn + j * 16 + ml;
    offB[j] = (r * 4 + (qk ^ ((r >> 1) & 3))) * 8;
  }

  f32x4 acc[8][4];
#pragma unroll
  for (int i = 0; i < 8; i++)
#pragma unroll
    for (int j = 0; j < 4; j++) acc[i][j] = (f32x4){0.f, 0.f, 0.f, 0.f};

  const int NT = K >> 6;

#define STG8(arrx, ksx, tilex, bufx) do {                                          \
    const u16* gsrc_ = (arrx) ? B : A;                                             \
    const size_t k_ = (size_t)(tilex) * 64 + (ksx) * 32;                           \
    u16* lb_ = &L[(bufx)][(arrx)][(ksx)][0];                                       \
    __builtin_amdgcn_global_load_lds(                                              \
        (const __attribute__((address_space(1))) void*)(gsrc_ + ((arrx) ? gb0 : ga0) + k_), \
        (__attribute__((address_space(3))) void*)(lb_ + tid * 8), 16, 0, 0);       \
    __builtin_amdgcn_global_load_lds(                                              \
        (const __attribute__((address_space(1))) void*)(gsrc_ + ((arrx) ? gb1 : ga1) + k_), \
        (__attribute__((address_space(3))) void*)(lb_ + (tid + 512) * 8), 16, 0, 0); \
  } while (0)

  // Prologue: tile0 fully, tile1's first 3 regions. vmcnt(6) -> tile0 landed.
  STG8(1, 0, 0, 0); STG8(0, 0, 0, 0); STG8(1, 1, 0, 0); STG8(0, 1, 0, 0);
  if (NT > 1) {
    STG8(1, 0, 1, 1); STG8(0, 0, 1, 1); STG8(1, 1, 1, 1);
    asm volatile("s_waitcnt vmcnt(6)" ::: "memory");
  } else {
    asm volatile("s_waitcnt vmcnt(0)" ::: "memory");
  }
  SB8; BAR8; SB8;

  for (int t = 0; t < NT; t++) {
    const int buf = t & 1;
    const u16* LA0 = &L[buf][0][0][0];
    const u16* LA1 = &L[buf][0][1][0];
    const u16* LB0 = &L[buf][1][0][0];
    const u16* LB1 = &L[buf][1][1][0];
    short8 afr[4], bfr[4];

    // ---- phase 0: ks0, frags 0-3
#pragma unroll
    for (int j = 0; j < 4; j++) bfr[j] = *(const short8*)(LB0 + offB[j]);
#pragma unroll
    for (int i = 0; i < 4; i++) afr[i] = *(const short8*)(LA0 + offA[i]);
    if (t + 1 < NT) STG8(0, 1, t + 1, (t + 1) & 1);
    SB8; BAR8;
    asm volatile("s_waitcnt lgkmcnt(0)" ::: "memory"); SB8;
    __builtin_amdgcn_s_setprio(1);
#pragma unroll
    for (int i = 0; i < 4; i++)
#pragma unroll
      for (int j = 0; j < 4; j++)
        acc[i][j] = __builtin_amdgcn_mfma_f32_16x16x32_bf16(afr[i], bfr[j], acc[i][j], 0, 0, 0);
    __builtin_amdgcn_s_setprio(0);
    SB8; BAR8;

    // ---- phase 1: ks0, frags 4-7 (reuse bfr)
#pragma unroll
    for (int i = 0; i < 4; i++) afr[i] = *(const short8*)(LA0 + offA[4 + i]);
    if (t + 2 < NT) STG8(1, 0, t + 2, buf);
    SB8; BAR8;
    asm volatile("s_waitcnt lgkmcnt(0)" ::: "memory"); SB8;
    __builtin_amdgcn_s_setprio(1);
#pragma unroll
    for (int i = 0; i < 4; i++)
#pragma unroll
      for (int j = 0; j < 4; j++)
        acc[4 + i][j] = __builtin_amdgcn_mfma_f32_16x16x32_bf16(afr[i], bfr[j], acc[4 + i][j], 0, 0, 0);
    __builtin_amdgcn_s_setprio(0);
    SB8; BAR8;

    // ---- phase 2: ks1, frags 0-3
#pragma unroll
    for (int j = 0; j < 4; j++) bfr[j] = *(const short8*)(LB1 + offB[j]);
#pragma unroll
    for (int i = 0; i < 4; i++) afr[i] = *(const short8*)(LA1 + offA[i]);
    if (t + 2 < NT) STG8(0, 0, t + 2, buf);
    SB8; BAR8;
    asm volatile("s_waitcnt lgkmcnt(0)" ::: "memory"); SB8;
    __builtin_amdgcn_s_setprio(1);
#pragma unroll
    for (int i = 0; i < 4; i++)
#pragma unroll
      for (int j = 0; j < 4; j++)
        acc[i][j] = __builtin_amdgcn_mfma_f32_16x16x32_bf16(afr[i], bfr[j], acc[i][j], 0, 0, 0);
    __builtin_amdgcn_s_setprio(0);
    SB8; BAR8;

    // ---- phase 3: ks1, frags 4-7 (reuse bfr); counted vmcnt
#pragma unroll
    for (int i = 0; i < 4; i++) afr[i] = *(const short8*)(LA1 + offA[4 + i]);
    if (t + 2 < NT) STG8(1, 1, t + 2, buf);
    if (t + 1 < NT) {
      if (t + 2 < NT) { asm volatile("s_waitcnt vmcnt(6)" ::: "memory"); }
      else            { asm volatile("s_waitcnt vmcnt(0)" ::: "memory"); }
    }
    SB8; BAR8;
    asm volatile("s_waitcnt lgkmcnt(0)" ::: "memory"); SB8;
    __builtin_amdgcn_s_setprio(1);
#pragma unroll
    for (int i = 0; i < 4; i++)
#pragma unroll
      for (int j = 0; j < 4; j++)
        acc[4 + i][j] = __builtin_amdgcn_mfma_f32_16x16x32_bf16(afr[i], bfr[j], acc[4 + i][j], 0, 0, 0);
    __builtin_amdgcn_s_setprio(0);
    SB8; BAR8;
  }
#undef STG8

  // Epilogue (same layout math as the 128x128 kernel).
  const int qr = (lane >> 4) * 4;
#pragma unroll
  for (int i = 0; i < 8; i++) {
#pragma unroll
    for (int j = 0; j < 4; j++) {
      const int colg = bn + wn + j * 16 + ml;
      const float bb = u2f(bias[colg]);
#pragma unroll
      for (int r = 0; r < 4; r++) {
        const size_t row = (size_t)row0 + bm + wm + i * 16 + qr + r;
        float v = acc[i][j][r] + bb;
        if (EPI == 1) v = gelu_exact(v);
        if (EPI == 2) {
          v += ld1(res, row * ldc + colg, fl);
          st1(C, row * ldc + colg, v, fl);
        } else {
          ((u16*)C)[row * ldc + colg] = f2u(v);
        }
      }
    }
  }
}

// ---------------------------------------------------------------------------
// Cluster kernel (round-6 structure; unchanged this round).
// ---------------------------------------------------------------------------
__global__ __launch_bounds__(512) void cluster_kernel(u16* __restrict__ FV,
                                                      const void* __restrict__ alpha_p,
                                                      const void* __restrict__ beta_p,
                                                      const int* __restrict__ flagp) {
  const int fl = flagp[0];
  const int be = blockIdx.x;       // 0..127
  const int b = be >> 3, e = be & 7;
  const int tid = threadIdx.x;
  const float alpha = ld1(alpha_p, 0, fl), beta = ld1(beta_p, 0, fl);

  __shared__ __align__(16) u16 S[1024 * 24];   // staged F, then V (48 KB)
  __shared__ float cn[16][24];
  __shared__ float vcen[16][24];
  __shared__ float outc[16][24];
  __shared__ float rcn[16];
  __shared__ int cnt[16];

  u16* Fg = FV + ((size_t)b * 1024) * 384 + e * 24;
  const u16* Vg = Fg + 192;

  for (int c = tid; c < 3072; c += 512) {
    const int n = c / 3, q = c - n * 3;
    *(uint4*)&S[n * 24 + q * 8] = *(const uint4*)(Fg + (size_t)n * 384 + q * 8);
  }
  if (tid < 16) cnt[tid] = 0;
  __syncthreads();

  for (int t = tid; t < 384; t += 512) {
    const int m = t / 24, ch = t - m * 24;
    const int pw = m >> 2, ph = m & 3;
    float sum = 0.f;
    for (int dw = 0; dw < 8; dw++) {
      const int base = (pw * 8 + dw) * 32 + ph * 8;
      for (int dh = 0; dh < 8; dh++) sum += u2f(S[(base + dh) * 24 + ch]);
    }
    cn[m][ch] = sum * (1.f / 64.f);
  }
  __syncthreads();
  if (tid < 16) {
    float s = 0.f;
    for (int ch = 0; ch < 24; ch++) { const float v = cn[tid][ch]; s += v * v; }
    rcn[tid] = 1.f / fmaxf(sqrtf(s), 1e-12f);
  }
  __syncthreads();

  const int na = tid, nb = tid + 512;
  float besta = -3.4e38f, bestb = -3.4e38f;
  int bma = 0, bmb = 0;
  {
    float xa[24], xb[24];
    const uint4* ra = (const uint4*)&S[na * 24];
    const uint4* rb = (const uint4*)&S[nb * 24];
#pragma unroll
    for (int q = 0; q < 3; q++) {
      unpack8(ra[q], &xa[q * 8]);
      unpack8(rb[q], &xb[q * 8]);
    }
    float ssa = 0.f, ssb = 0.f;
#pragma unroll
    for (int ch = 0; ch < 24; ch++) {
      ssa = fmaf(xa[ch], xa[ch], ssa);
      ssb = fmaf(xb[ch], xb[ch], ssb);
    }
    const float rna = 1.f / fmaxf(sqrtf(ssa), 1e-12f);
    const float rnb = 1.f / fmaxf(sqrtf(ssb), 1e-12f);
    for (int m = 0; m < 16; m++) {
      float da = 0.f, db = 0.f;
#pragma unroll
      for (int k = 0; k < 12; k++) {
        const float2 c = *(const float2*)&cn[m][2 * k];
        da = fmaf(c.x, xa[2 * k], da); da = fmaf(c.y, xa[2 * k + 1], da);
        db = fmaf(c.x, xb[2 * k], db); db = fmaf(c.y, xb[2 * k + 1], db);
      }
      const float rc = rcn[m];
      da *= rna * rc;
      db *= rnb * rc;
      const float dda = sqrtf(fmaxf(2.f - 2.f * da, 1e-12f));
      const float ddb = sqrtf(fmaxf(2.f - 2.f * db, 1e-12f));
      const float za = beta + alpha * expf(-dda);
      const float zb = beta + alpha * expf(-ddb);
      const float sa = (za >= 0.f) ? za : 0.2f * za;
      const float sb = (zb >= 0.f) ? zb : 0.2f * zb;
      if (sa > besta) { besta = sa; bma = m; }
      if (sb > bestb) { bestb = sb; bmb = m; }
    }
    atomicAdd(&cnt[bma], 1);
    atomicAdd(&cnt[bmb], 1);
  }
  __syncthreads();

  for (int c = tid; c < 3072; c += 512) {
    const int n = c / 3, q = c - n * 3;
    *(uint4*)&S[n * 24 + q * 8] = *(const uint4*)(Vg + (size_t)n * 384 + q * 8);
  }
  if (tid < 384) outc[tid / 24][tid - (tid / 24) * 24] = 0.f;
  __syncthreads();

  for (int t = tid; t < 384; t += 512) {
    const int m = t / 24, ch = t - m * 24;
    const int pw = m >> 2, ph = m & 3;
    float sum = 0.f;
    for (int dw = 0; dw < 8; dw++) {
      const int base = (pw * 8 + dw) * 32 + ph * 8;
      for (int dh = 0; dh < 8; dh++) sum += u2f(S[(base + dh) * 24 + ch]);
    }
    vcen[m][ch] = sum * (1.f / 64.f);
  }

  {
    float va[24], vb[24];
    const uint4* ra = (const uint4*)&S[na * 24];
    const uint4* rb = (const uint4*)&S[nb * 24];
#pragma unroll
    for (int q = 0; q < 3; q++) {
      unpack8(ra[q], &va[q * 8]);
      unpack8(rb[q], &vb[q * 8]);
    }
#pragma unroll
    for (int ch = 0; ch < 24; ch++) {
      atomicAdd(&outc[bma][ch], besta * va[ch]);
      atomicAdd(&outc[bmb][ch], bestb * vb[ch]);
    }
  }
  __syncthreads();

  for (int t = tid; t < 384; t += 512) {
    const int m = t / 24, ch = t - m * 24;
    outc[m][ch] = (outc[m][ch] + vcen[m][ch]) / ((float)cnt[m] + 1.f);
  }
  __syncthreads();

#pragma unroll
  for (int pass = 0; pass < 2; pass++) {
    const int n = pass ? nb : na;
    const int m = pass ? bmb : bma;
    const float s = pass ? bestb : besta;
    unsigned w[12];
#pragma unroll
    for (int k = 0; k < 12; k++) {
      w[k] = (unsigned)f2u(s * outc[m][2 * k]) |
             ((unsigned)f2u(s * outc[m][2 * k + 1]) << 16);
    }
    uint4* dst = (uint4*)(Fg + (size_t)n * 384);
    dst[0] = make_uint4(w[0], w[1], w[2], w[3]);
    dst[1] = make_uint4(w[4], w[5], w[6], w[7]);
    dst[2] = make_uint4(w[8], w[9], w[10], w[11]);
  }
}

// ---------------------------------------------------------------------------
// Workspace layout (floor 48.1 MB; G beyond that, adaptive):
//   flag @0 | fv_w @256 | proj_w @590080 | fc1_w @884992 | fc2_w @5603584
//   fvb @10322176 | projb @10322944 | fc1b @10324480 | fc2b @10330624
//   Y1 bf16 16384x768 @10332416 | FV bf16 16384x384 @35498240 | G @48081152
// ---------------------------------------------------------------------------
extern "C" void kernel_launch(void* const* d_in, const int* in_sizes, int n_in,
                              void* d_out, int out_size, void* d_ws, size_t ws_size,
                              hipStream_t stream) {
  const void* x      = d_in[0];
  const void* ln1_w  = d_in[1];
  const void* ln1_b  = d_in[2];
  const void* f_w    = d_in[3];
  const void* f_b    = d_in[4];
  const void* v_w    = d_in[5];
  const void* v_b    = d_in[6];
  const void* proj_w = d_in[7];
  const void* proj_b = d_in[8];
  const void* alpha  = d_in[9];
  const void* beta   = d_in[10];
  const void* ln2_w  = d_in[11];
  const void* ln2_b  = d_in[12];
  const void* fc1_w  = d_in[13];
  const void* fc1_b  = d_in[14];
  const void* fc2_w  = d_in[15];
  const void* fc2_b  = d_in[16];

  char* ws = (char*)d_ws;
  int* flag  = (int*)(ws + 0);
  u16* fvw   = (u16*)(ws + 256);
  u16* prw   = (u16*)(ws + 590080);
  u16* f1w   = (u16*)(ws + 884992);
  u16* f2w   = (u16*)(ws + 5603584);
  u16* fvb   = (u16*)(ws + 10322176);
  u16* prb   = (u16*)(ws + 10322944);
  u16* f1b   = (u16*)(ws + 10324480);
  u16* f2b_  = (u16*)(ws + 10330624);
  u16* Y1    = (u16*)(ws + 10332416);
  u16* FV    = (u16*)(ws + 35498240);
  u16* Gext  = (u16*)(ws + 48081152);

  // fc1/fc2 chunk rows (multiple of 256 for the 256-tile GEMM).
  const long extra = (long)ws_size - 48081152L;
  u16* G; long crows;
  if (extra >= (long)NTOK * HID_ * 2) { G = Gext; crows = NTOK; }
  else if (extra >= 256L * HID_ * 2) { G = Gext; crows = (extra / (HID_ * 2)) / 256 * 256; }
  else { G = FV; crows = 2048; }  // FV dead after proj; 2048*3072*2 = 12.58 MB fits

  detect_kernel<<<1, 64, 0, stream>>>((const unsigned*)x, flag);

  CvtArgs ca;
  ca.j[0] = {f_w,    fvw,            147456 / 4};
  ca.j[1] = {v_w,    fvw + 147456,   147456 / 4};
  ca.j[2] = {proj_w, prw,            147456 / 4};
  ca.j[3] = {fc1_w,  f1w,            2359296 / 4};
  ca.j[4] = {fc2_w,  f2w,            2359296 / 4};
  ca.j[5] = {f_b,    fvb,            192 / 4};
  ca.j[6] = {v_b,    fvb + 192,      192 / 4};
  ca.j[7] = {proj_b, prb,            768 / 4};
  ca.j[8] = {fc1_b,  f1b,            3072 / 4};
  ca.j[9] = {fc2_b,  f2b_,           768 / 4};
  cvt_kernel<<<dim3(2304, 10), 256, 0, stream>>>(ca, flag);

  // ln1(x) -> Y1 (bf16)
  ln_kernel<<<NTOK, 256, 0, stream>>>(x, ln1_w, ln1_b, Y1, flag);
  // FV = Y1 * [f_w; v_w]^T + [f_b; v_b]   (M=16384, N=384, K=768)
  mfma_gemm<0><<<dim3(128, 3), 256, 0, stream>>>(
      Y1, D_, fvw, D_, fvb, nullptr, FV, 384, D_, 0, flag);
  cluster_kernel<<<128, 512, 0, stream>>>(FV, alpha, beta, flag);
  // h = CL * proj_w^T + proj_b + x -> d_out (flag dtype). A = FV cols [0,192).
  mfma_gemm<2><<<dim3(128, 6), 256, 0, stream>>>(
      FV, 384, prw, INNER_, prb, x, d_out, D_, INNER_, 0, flag);
  // ln2(h) -> Y1 (bf16)
  ln_kernel<<<NTOK, 256, 0, stream>>>(d_out, ln2_w, ln2_b, Y1, flag);
  // fc1 -> G (gelu), fc2 + h residual -> d_out in place, chunked (256-tile)
  for (long t0 = 0; t0 < NTOK; t0 += crows) {
    const long ct = (t0 + crows <= NTOK) ? crows : (NTOK - t0);
    mfma_gemm8<1><<<dim3(ct / 256, HID_ / 256), 512, 0, stream>>>(
        Y1 + t0 * D_, D_, f1w, D_, f1b, nullptr, G, HID_, D_, 0, flag);
    mfma_gemm8<2><<<dim3(ct / 256, D_ / 256), 512, 0, stream>>>(
        G, HID_, f2w, HID_, f2b_, d_out, d_out, D_, HID_, (int)t0, flag);
  }
}

// Round 3
// 522.489 us; speedup vs baseline: 1.0116x; 1.0116x over previous
//
#include <hip/hip_runtime.h>
#include <hip/hip_bf16.h>
#include <cmath>

typedef unsigned short u16;
typedef short short8 __attribute__((ext_vector_type(8)));   // 8 bf16 (4 VGPRs)
typedef float f32x4 __attribute__((ext_vector_type(4)));    // 4 fp32 acc

#define D_ 768
#define NTOK 16384      // B * N = 16 * 1024
#define INNER_ 192
#define HID_ 3072

__device__ __forceinline__ float u2f(u16 u) { return __uint_as_float((unsigned)u << 16); }
__device__ __forceinline__ u16 f2u(float f) {
  __hip_bfloat16 h = __float2bfloat16(f);
  u16 u; __builtin_memcpy(&u, &h, 2); return u;
}
// Flag-aware scalar load/store: harness tensors are f32 (flag=1) or bf16 (0).
__device__ __forceinline__ float ld1(const void* p, size_t i, int f32) {
  return f32 ? ((const float*)p)[i] : u2f(((const u16*)p)[i]);
}
__device__ __forceinline__ void st1(void* p, size_t i, float v, int f32) {
  if (f32) ((float*)p)[i] = v; else ((u16*)p)[i] = f2u(v);
}
__device__ __forceinline__ float gelu_exact(float v) {
  return 0.5f * v * (1.f + erff(v * 0.7071067811865476f));
}
// Unpack 8 bf16 (uint4) -> 8 f32.
__device__ __forceinline__ void unpack8(const uint4 v, float* o) {
  o[0] = u2f((u16)(v.x & 0xffffu)); o[1] = u2f((u16)(v.x >> 16));
  o[2] = u2f((u16)(v.y & 0xffffu)); o[3] = u2f((u16)(v.y >> 16));
  o[4] = u2f((u16)(v.z & 0xffffu)); o[5] = u2f((u16)(v.z >> 16));
  o[6] = u2f((u16)(v.w & 0xffffu)); o[7] = u2f((u16)(v.w >> 16));
}

// ---------------------------------------------------------------------------
// Dtype detector (verified round 4/5): flag 1 = f32 inputs, 0 = bf16 inputs.
// ---------------------------------------------------------------------------
__global__ __launch_bounds__(64) void detect_kernel(const unsigned* __restrict__ x,
                                                    int* __restrict__ flag) {
  int cnt = 0;
  for (int i = threadIdx.x; i < 512; i += 64) {
    const unsigned e0 = (x[i] >> 7) & 0xFFu;
    if (e0 >= 96u && e0 <= 144u) cnt++;
  }
#pragma unroll
  for (int o = 32; o > 0; o >>= 1) cnt += __shfl_down(cnt, o);
  if (threadIdx.x == 0) flag[0] = (cnt < 256) ? 1 : 0;
}

// ---------------------------------------------------------------------------
// Weight conversion to internal bf16 (10 jobs; grid.y = job id).
// ---------------------------------------------------------------------------
struct CvtJob { const void* src; u16* dst; int n4; };  // n4 = elems/4
struct CvtArgs { CvtJob j[10]; };

__global__ __launch_bounds__(256) void cvt_kernel(CvtArgs a, const int* __restrict__ flagp) {
  const int f32 = flagp[0];
  const CvtJob jb = a.j[blockIdx.y];
  const int i = blockIdx.x * 256 + threadIdx.x;
  if (i >= jb.n4) return;
  if (f32) {
    const float4 v = ((const float4*)jb.src)[i];
    const unsigned lo = (unsigned)f2u(v.x) | ((unsigned)f2u(v.y) << 16);
    const unsigned hi = (unsigned)f2u(v.z) | ((unsigned)f2u(v.w) << 16);
    ((uint2*)jb.dst)[i] = make_uint2(lo, hi);
  } else {
    ((uint2*)jb.dst)[i] = ((const uint2*)jb.src)[i];
  }
}

// ---------------------------------------------------------------------------
// Fused LayerNorm: stats + normalize, one block (256 thr) per token.
// ---------------------------------------------------------------------------
__global__ __launch_bounds__(256) void ln_kernel(const void* __restrict__ x,
                                                 const void* __restrict__ w,
                                                 const void* __restrict__ b,
                                                 u16* __restrict__ y,
                                                 const int* __restrict__ flagp) {
  const int fl = flagp[0];
  const size_t t = blockIdx.x;
  float v[3];
  float s = 0.f, s2 = 0.f;
#pragma unroll
  for (int i = 0; i < 3; i++) {
    v[i] = ld1(x, t * D_ + threadIdx.x + 256 * i, fl);
    s += v[i];
    s2 += v[i] * v[i];
  }
#pragma unroll
  for (int o = 32; o > 0; o >>= 1) {
    s += __shfl_down(s, o);
    s2 += __shfl_down(s2, o);
  }
  __shared__ float ps[4], ps2[4];
  __shared__ float smu, srstd;
  const int wid = threadIdx.x >> 6, lane = threadIdx.x & 63;
  if (lane == 0) { ps[wid] = s; ps2[wid] = s2; }
  __syncthreads();
  if (threadIdx.x == 0) {
    const float a = ps[0] + ps[1] + ps[2] + ps[3];
    const float a2 = ps2[0] + ps2[1] + ps2[2] + ps2[3];
    const float mu = a * (1.f / D_);
    smu = mu;
    srstd = rsqrtf(a2 * (1.f / D_) - mu * mu + 1e-5f);
  }
  __syncthreads();
  const float mu = smu, rstd = srstd;
#pragma unroll
  for (int i = 0; i < 3; i++) {
    const int c = threadIdx.x + 256 * i;
    y[t * D_ + c] = f2u((v[i] - mu) * rstd * ld1(w, c, fl) + ld1(b, c, fl));
  }
}

// ---------------------------------------------------------------------------
// MFMA GEMM (m97 structure, 128x128): kept for fv (N=384) and proj (K=192).
// ---------------------------------------------------------------------------
template <int EPI>
__global__ __launch_bounds__(256) void mfma_gemm(const u16* __restrict__ A, int lda,
                                                 const u16* __restrict__ B, int ldb,
                                                 const u16* __restrict__ bias,
                                                 const void* __restrict__ res,
                                                 void* __restrict__ C, int ldc,
                                                 int K, int row0,
                                                 const int* __restrict__ flagp) {
  const int fl = flagp[0];
  __shared__ __align__(16) u16 Asb[128 * 32];
  __shared__ __align__(16) u16 Bsb[128 * 32];
  const int tid = threadIdx.x;
  const int lane = tid & 63;
  const int wv = tid >> 6;
  const int bm = blockIdx.x * 128;
  const int bn = blockIdx.y * 128;
  const int wm = (wv & 1) * 64;
  const int wn = (wv >> 1) * 64;
  const int c0 = tid, c1 = tid + 256;
  const u16* Ag0 = A + (size_t)(bm + (c0 >> 2)) * lda + (c0 & 3) * 8;
  const u16* Ag1 = A + (size_t)(bm + (c1 >> 2)) * lda + (c1 & 3) * 8;
  const u16* Bg0 = B + (size_t)(bn + (c0 >> 2)) * ldb + (c0 & 3) * 8;
  const u16* Bg1 = B + (size_t)(bn + (c1 >> 2)) * ldb + (c1 & 3) * 8;
  u16* la0 = &Asb[c0 * 8];
  u16* la1 = &Asb[c1 * 8];
  u16* lb0 = &Bsb[c0 * 8];
  u16* lb1 = &Bsb[c1 * 8];

  f32x4 acc[4][4];
#pragma unroll
  for (int i = 0; i < 4; i++)
#pragma unroll
    for (int j = 0; j < 4; j++) acc[i][j] = (f32x4){0.f, 0.f, 0.f, 0.f};

  const int ml = lane & 15;
  const int kq = (lane >> 4) * 8;

  for (int k0 = 0; k0 < K; k0 += 32) {
    __syncthreads();
    __builtin_amdgcn_global_load_lds(
        (const __attribute__((address_space(1))) void*)(Ag0 + k0),
        (__attribute__((address_space(3))) void*)la0, 16, 0, 0);
    __builtin_amdgcn_global_load_lds(
        (const __attribute__((address_space(1))) void*)(Ag1 + k0),
        (__attribute__((address_space(3))) void*)la1, 16, 0, 0);
    __builtin_amdgcn_global_load_lds(
        (const __attribute__((address_space(1))) void*)(Bg0 + k0),
        (__attribute__((address_space(3))) void*)lb0, 16, 0, 0);
    __builtin_amdgcn_global_load_lds(
        (const __attribute__((address_space(1))) void*)(Bg1 + k0),
        (__attribute__((address_space(3))) void*)lb1, 16, 0, 0);
    __syncthreads();
    short8 af[4], bf[4];
#pragma unroll
    for (int i = 0; i < 4; i++) {
      af[i] = *(const short8*)&Asb[(wm + i * 16 + ml) * 32 + kq];
      bf[i] = *(const short8*)&Bsb[(wn + i * 16 + ml) * 32 + kq];
    }
#pragma unroll
    for (int i = 0; i < 4; i++)
#pragma unroll
      for (int j = 0; j < 4; j++)
        acc[i][j] = __builtin_amdgcn_mfma_f32_16x16x32_bf16(af[i], bf[j], acc[i][j], 0, 0, 0);
  }

  const int qr = (lane >> 4) * 4;
#pragma unroll
  for (int i = 0; i < 4; i++) {
#pragma unroll
    for (int j = 0; j < 4; j++) {
      const int colg = bn + wn + j * 16 + ml;
      const float bb = u2f(bias[colg]);
#pragma unroll
      for (int r = 0; r < 4; r++) {
        const size_t row = (size_t)row0 + bm + wm + i * 16 + qr + r;
        float v = acc[i][j][r] + bb;
        if (EPI == 1) v = gelu_exact(v);
        if (EPI == 2) {
          v += ld1(res, row * ldc + colg, fl);
          st1(C, row * ldc + colg, v, fl);
        } else {
          ((u16*)C)[row * ldc + colg] = f2u(v);
        }
      }
    }
  }
}

// ---------------------------------------------------------------------------
// 8-phase 256x256 MFMA GEMM (T2+T3+T4+T5) with XCD panel-grouped remap (T1).
// 1D grid of gm*gn blocks. If gm % 8 == 0: XCD x = bid&7 owns M-blocks
// [x*gm/8, (x+1)*gm/8), swept M-fastest (mloc = slot % mpx, n = slot / mpx)
// so the ~32 co-resident blocks per XCD share an L2-resident A-stripe and a
// few B-panels (round-2 evidence: without this, panel re-reads are L3-served
// and stall the pipeline at 24% MfmaUtil).
// Schedule per tile t (buf = t&1), phases j0..j3 as in round 2; vmcnt(6)
// once per tile; LDS XOR-swizzle both-sides. Accumulation order identical
// to the 128x128 kernel.
// Requires M%256==0, N%256==0, K%64==0, K>=128.
// ---------------------------------------------------------------------------
#define SB8 __builtin_amdgcn_sched_barrier(0)
#define BAR8 __builtin_amdgcn_s_barrier()

template <int EPI>
__global__ __launch_bounds__(512) void mfma_gemm8(const u16* __restrict__ A, int lda,
                                                  const u16* __restrict__ B, int ldb,
                                                  const u16* __restrict__ bias,
                                                  const void* __restrict__ res,
                                                  void* __restrict__ C, int ldc,
                                                  int K, int row0, int gm, int gn,
                                                  const int* __restrict__ flagp) {
  const int fl = flagp[0];
  __shared__ __align__(16) u16 L[2][2][2][8192];  // [buf][A=0/B=1][ks][256*32]
  const int tid = threadIdx.x;
  const int lane = tid & 63;
  const int wv = tid >> 6;

  // ---- XCD panel-grouped block remap (bijective; identity fallback).
  int mb_, nb_;
  {
    const int bid = blockIdx.x;
    if ((gm & 7) == 0) {
      const int xcd = bid & 7;
      const int slot = bid >> 3;
      const int mpx = gm >> 3;          // M-blocks per XCD
      mb_ = xcd * mpx + (slot % mpx);   // M fastest within XCD
      nb_ = slot / mpx;
    } else {
      mb_ = bid % gm;
      nb_ = bid / gm;
    }
  }
  const int bm = mb_ * 256;
  const int bn = nb_ * 256;

  const int wm = (wv >> 2) * 128;   // 0 or 128
  const int wn = (wv & 3) * 64;
  const int ml = lane & 15;
  const int qk = lane >> 4;         // 16B chunk within k-slice

  // Staging geometry: thread covers region chunks c = tid and tid+512;
  // row = c>>2, slot = c&3, global chunk q = slot ^ ((row>>1)&3).
  const int srow = tid >> 2;                      // 0..127
  const int q_s = (tid & 3) ^ ((srow >> 1) & 3);  // same for row and row+128
  const size_t ga0 = (size_t)(bm + srow) * lda + q_s * 8;
  const size_t ga1 = (size_t)(bm + srow + 128) * lda + q_s * 8;
  const size_t gb0 = (size_t)(bn + srow) * ldb + q_s * 8;
  const size_t gb1 = (size_t)(bn + srow + 128) * ldb + q_s * 8;

  // LDS read offsets (elems within a 256x32 region), swizzled.
  int offA[8], offB[4];
#pragma unroll
  for (int i = 0; i < 8; i++) {
    const int r = wm + i * 16 + ml;
    offA[i] = (r * 4 + (qk ^ ((r >> 1) & 3))) * 8;
  }
#pragma unroll
  for (int j = 0; j < 4; j++) {
    const int r = wn + j * 16 + ml;
    offB[j] = (r * 4 + (qk ^ ((r >> 1) & 3))) * 8;
  }

  f32x4 acc[8][4];
#pragma unroll
  for (int i = 0; i < 8; i++)
#pragma unroll
    for (int j = 0; j < 4; j++) acc[i][j] = (f32x4){0.f, 0.f, 0.f, 0.f};

  const int NT = K >> 6;

#define STG8(arrx, ksx, tilex, bufx) do {                                          \
    const u16* gsrc_ = (arrx) ? B : A;                                             \
    const size_t k_ = (size_t)(tilex) * 64 + (ksx) * 32;                           \
    u16* lb_ = &L[(bufx)][(arrx)][(ksx)][0];                                       \
    __builtin_amdgcn_global_load_lds(                                              \
        (const __attribute__((address_space(1))) void*)(gsrc_ + ((arrx) ? gb0 : ga0) + k_), \
        (__attribute__((address_space(3))) void*)(lb_ + tid * 8), 16, 0, 0);       \
    __builtin_amdgcn_global_load_lds(                                              \
        (const __attribute__((address_space(1))) void*)(gsrc_ + ((arrx) ? gb1 : ga1) + k_), \
        (__attribute__((address_space(3))) void*)(lb_ + (tid + 512) * 8), 16, 0, 0); \
  } while (0)

  // Prologue: tile0 fully, tile1's first 3 regions. vmcnt(6) -> tile0 landed.
  STG8(1, 0, 0, 0); STG8(0, 0, 0, 0); STG8(1, 1, 0, 0); STG8(0, 1, 0, 0);
  if (NT > 1) {
    STG8(1, 0, 1, 1); STG8(0, 0, 1, 1); STG8(1, 1, 1, 1);
    asm volatile("s_waitcnt vmcnt(6)" ::: "memory");
  } else {
    asm volatile("s_waitcnt vmcnt(0)" ::: "memory");
  }
  SB8; BAR8; SB8;

  for (int t = 0; t < NT; t++) {
    const int buf = t & 1;
    const u16* LA0 = &L[buf][0][0][0];
    const u16* LA1 = &L[buf][0][1][0];
    const u16* LB0 = &L[buf][1][0][0];
    const u16* LB1 = &L[buf][1][1][0];
    short8 afr[4], bfr[4];

    // ---- phase 0: ks0, frags 0-3
#pragma unroll
    for (int j = 0; j < 4; j++) bfr[j] = *(const short8*)(LB0 + offB[j]);
#pragma unroll
    for (int i = 0; i < 4; i++) afr[i] = *(const short8*)(LA0 + offA[i]);
    if (t + 1 < NT) STG8(0, 1, t + 1, (t + 1) & 1);
    SB8; BAR8;
    asm volatile("s_waitcnt lgkmcnt(0)" ::: "memory"); SB8;
    __builtin_amdgcn_s_setprio(1);
#pragma unroll
    for (int i = 0; i < 4; i++)
#pragma unroll
      for (int j = 0; j < 4; j++)
        acc[i][j] = __builtin_amdgcn_mfma_f32_16x16x32_bf16(afr[i], bfr[j], acc[i][j], 0, 0, 0);
    __builtin_amdgcn_s_setprio(0);
    SB8; BAR8;

    // ---- phase 1: ks0, frags 4-7 (reuse bfr)
#pragma unroll
    for (int i = 0; i < 4; i++) afr[i] = *(const short8*)(LA0 + offA[4 + i]);
    if (t + 2 < NT) STG8(1, 0, t + 2, buf);
    SB8; BAR8;
    asm volatile("s_waitcnt lgkmcnt(0)" ::: "memory"); SB8;
    __builtin_amdgcn_s_setprio(1);
#pragma unroll
    for (int i = 0; i < 4; i++)
#pragma unroll
      for (int j = 0; j < 4; j++)
        acc[4 + i][j] = __builtin_amdgcn_mfma_f32_16x16x32_bf16(afr[i], bfr[j], acc[4 + i][j], 0, 0, 0);
    __builtin_amdgcn_s_setprio(0);
    SB8; BAR8;

    // ---- phase 2: ks1, frags 0-3
#pragma unroll
    for (int j = 0; j < 4; j++) bfr[j] = *(const short8*)(LB1 + offB[j]);
#pragma unroll
    for (int i = 0; i < 4; i++) afr[i] = *(const short8*)(LA1 + offA[i]);
    if (t + 2 < NT) STG8(0, 0, t + 2, buf);
    SB8; BAR8;
    asm volatile("s_waitcnt lgkmcnt(0)" ::: "memory"); SB8;
    __builtin_amdgcn_s_setprio(1);
#pragma unroll
    for (int i = 0; i < 4; i++)
#pragma unroll
      for (int j = 0; j < 4; j++)
        acc[i][j] = __builtin_amdgcn_mfma_f32_16x16x32_bf16(afr[i], bfr[j], acc[i][j], 0, 0, 0);
    __builtin_amdgcn_s_setprio(0);
    SB8; BAR8;

    // ---- phase 3: ks1, frags 4-7 (reuse bfr); counted vmcnt
#pragma unroll
    for (int i = 0; i < 4; i++) afr[i] = *(const short8*)(LA1 + offA[4 + i]);
    if (t + 2 < NT) STG8(1, 1, t + 2, buf);
    if (t + 1 < NT) {
      if (t + 2 < NT) { asm volatile("s_waitcnt vmcnt(6)" ::: "memory"); }
      else            { asm volatile("s_waitcnt vmcnt(0)" ::: "memory"); }
    }
    SB8; BAR8;
    asm volatile("s_waitcnt lgkmcnt(0)" ::: "memory"); SB8;
    __builtin_amdgcn_s_setprio(1);
#pragma unroll
    for (int i = 0; i < 4; i++)
#pragma unroll
      for (int j = 0; j < 4; j++)
        acc[4 + i][j] = __builtin_amdgcn_mfma_f32_16x16x32_bf16(afr[i], bfr[j], acc[4 + i][j], 0, 0, 0);
    __builtin_amdgcn_s_setprio(0);
    SB8; BAR8;
  }
#undef STG8

  // Epilogue (same layout math as the 128x128 kernel).
  const int qr = (lane >> 4) * 4;
#pragma unroll
  for (int i = 0; i < 8; i++) {
#pragma unroll
    for (int j = 0; j < 4; j++) {
      const int colg = bn + wn + j * 16 + ml;
      const float bb = u2f(bias[colg]);
#pragma unroll
      for (int r = 0; r < 4; r++) {
        const size_t row = (size_t)row0 + bm + wm + i * 16 + qr + r;
        float v = acc[i][j][r] + bb;
        if (EPI == 1) v = gelu_exact(v);
        if (EPI == 2) {
          v += ld1(res, row * ldc + colg, fl);
          st1(C, row * ldc + colg, v, fl);
        } else {
          ((u16*)C)[row * ldc + colg] = f2u(v);
        }
      }
    }
  }
}

// ---------------------------------------------------------------------------
// Cluster kernel (round-6 structure; unchanged this round).
// ---------------------------------------------------------------------------
__global__ __launch_bounds__(512) void cluster_kernel(u16* __restrict__ FV,
                                                      const void* __restrict__ alpha_p,
                                                      const void* __restrict__ beta_p,
                                                      const int* __restrict__ flagp) {
  const int fl = flagp[0];
  const int be = blockIdx.x;       // 0..127
  const int b = be >> 3, e = be & 7;
  const int tid = threadIdx.x;
  const float alpha = ld1(alpha_p, 0, fl), beta = ld1(beta_p, 0, fl);

  __shared__ __align__(16) u16 S[1024 * 24];   // staged F, then V (48 KB)
  __shared__ float cn[16][24];
  __shared__ float vcen[16][24];
  __shared__ float outc[16][24];
  __shared__ float rcn[16];
  __shared__ int cnt[16];

  u16* Fg = FV + ((size_t)b * 1024) * 384 + e * 24;
  const u16* Vg = Fg + 192;

  for (int c = tid; c < 3072; c += 512) {
    const int n = c / 3, q = c - n * 3;
    *(uint4*)&S[n * 24 + q * 8] = *(const uint4*)(Fg + (size_t)n * 384 + q * 8);
  }
  if (tid < 16) cnt[tid] = 0;
  __syncthreads();

  for (int t = tid; t < 384; t += 512) {
    const int m = t / 24, ch = t - m * 24;
    const int pw = m >> 2, ph = m & 3;
    float sum = 0.f;
    for (int dw = 0; dw < 8; dw++) {
      const int base = (pw * 8 + dw) * 32 + ph * 8;
      for (int dh = 0; dh < 8; dh++) sum += u2f(S[(base + dh) * 24 + ch]);
    }
    cn[m][ch] = sum * (1.f / 64.f);
  }
  __syncthreads();
  if (tid < 16) {
    float s = 0.f;
    for (int ch = 0; ch < 24; ch++) { const float v = cn[tid][ch]; s += v * v; }
    rcn[tid] = 1.f / fmaxf(sqrtf(s), 1e-12f);
  }
  __syncthreads();

  const int na = tid, nb = tid + 512;
  float besta = -3.4e38f, bestb = -3.4e38f;
  int bma = 0, bmb = 0;
  {
    float xa[24], xb[24];
    const uint4* ra = (const uint4*)&S[na * 24];
    const uint4* rb = (const uint4*)&S[nb * 24];
#pragma unroll
    for (int q = 0; q < 3; q++) {
      unpack8(ra[q], &xa[q * 8]);
      unpack8(rb[q], &xb[q * 8]);
    }
    float ssa = 0.f, ssb = 0.f;
#pragma unroll
    for (int ch = 0; ch < 24; ch++) {
      ssa = fmaf(xa[ch], xa[ch], ssa);
      ssb = fmaf(xb[ch], xb[ch], ssb);
    }
    const float rna = 1.f / fmaxf(sqrtf(ssa), 1e-12f);
    const float rnb = 1.f / fmaxf(sqrtf(ssb), 1e-12f);
    for (int m = 0; m < 16; m++) {
      float da = 0.f, db = 0.f;
#pragma unroll
      for (int k = 0; k < 12; k++) {
        const float2 c = *(const float2*)&cn[m][2 * k];
        da = fmaf(c.x, xa[2 * k], da); da = fmaf(c.y, xa[2 * k + 1], da);
        db = fmaf(c.x, xb[2 * k], db); db = fmaf(c.y, xb[2 * k + 1], db);
      }
      const float rc = rcn[m];
      da *= rna * rc;
      db *= rnb * rc;
      const float dda = sqrtf(fmaxf(2.f - 2.f * da, 1e-12f));
      const float ddb = sqrtf(fmaxf(2.f - 2.f * db, 1e-12f));
      const float za = beta + alpha * expf(-dda);
      const float zb = beta + alpha * expf(-ddb);
      const float sa = (za >= 0.f) ? za : 0.2f * za;
      const float sb = (zb >= 0.f) ? zb : 0.2f * zb;
      if (sa > besta) { besta = sa; bma = m; }
      if (sb > bestb) { bestb = sb; bmb = m; }
    }
    atomicAdd(&cnt[bma], 1);
    atomicAdd(&cnt[bmb], 1);
  }
  __syncthreads();

  for (int c = tid; c < 3072; c += 512) {
    const int n = c / 3, q = c - n * 3;
    *(uint4*)&S[n * 24 + q * 8] = *(const uint4*)(Vg + (size_t)n * 384 + q * 8);
  }
  if (tid < 384) outc[tid / 24][tid - (tid / 24) * 24] = 0.f;
  __syncthreads();

  for (int t = tid; t < 384; t += 512) {
    const int m = t / 24, ch = t - m * 24;
    const int pw = m >> 2, ph = m & 3;
    float sum = 0.f;
    for (int dw = 0; dw < 8; dw++) {
      const int base = (pw * 8 + dw) * 32 + ph * 8;
      for (int dh = 0; dh < 8; dh++) sum += u2f(S[(base + dh) * 24 + ch]);
    }
    vcen[m][ch] = sum * (1.f / 64.f);
  }

  {
    float va[24], vb[24];
    const uint4* ra = (const uint4*)&S[na * 24];
    const uint4* rb = (const uint4*)&S[nb * 24];
#pragma unroll
    for (int q = 0; q < 3; q++) {
      unpack8(ra[q], &va[q * 8]);
      unpack8(rb[q], &vb[q * 8]);
    }
#pragma unroll
    for (int ch = 0; ch < 24; ch++) {
      atomicAdd(&outc[bma][ch], besta * va[ch]);
      atomicAdd(&outc[bmb][ch], bestb * vb[ch]);
    }
  }
  __syncthreads();

  for (int t = tid; t < 384; t += 512) {
    const int m = t / 24, ch = t - m * 24;
    outc[m][ch] = (outc[m][ch] + vcen[m][ch]) / ((float)cnt[m] + 1.f);
  }
  __syncthreads();

#pragma unroll
  for (int pass = 0; pass < 2; pass++) {
    const int n = pass ? nb : na;
    const int m = pass ? bmb : bma;
    const float s = pass ? bestb : besta;
    unsigned w[12];
#pragma unroll
    for (int k = 0; k < 12; k++) {
      w[k] = (unsigned)f2u(s * outc[m][2 * k]) |
             ((unsigned)f2u(s * outc[m][2 * k + 1]) << 16);
    }
    uint4* dst = (uint4*)(Fg + (size_t)n * 384);
    dst[0] = make_uint4(w[0], w[1], w[2], w[3]);
    dst[1] = make_uint4(w[4], w[5], w[6], w[7]);
    dst[2] = make_uint4(w[8], w[9], w[10], w[11]);
  }
}

// ---------------------------------------------------------------------------
// Workspace layout (floor 48.1 MB; G beyond that, adaptive):
//   flag @0 | fv_w @256 | proj_w @590080 | fc1_w @884992 | fc2_w @5603584
//   fvb @10322176 | projb @10322944 | fc1b @10324480 | fc2b @10330624
//   Y1 bf16 16384x768 @10332416 | FV bf16 16384x384 @35498240 | G @48081152
// ---------------------------------------------------------------------------
extern "C" void kernel_launch(void* const* d_in, const int* in_sizes, int n_in,
                              void* d_out, int out_size, void* d_ws, size_t ws_size,
                              hipStream_t stream) {
  const void* x      = d_in[0];
  const void* ln1_w  = d_in[1];
  const void* ln1_b  = d_in[2];
  const void* f_w    = d_in[3];
  const void* f_b    = d_in[4];
  const void* v_w    = d_in[5];
  const void* v_b    = d_in[6];
  const void* proj_w = d_in[7];
  const void* proj_b = d_in[8];
  const void* alpha  = d_in[9];
  const void* beta   = d_in[10];
  const void* ln2_w  = d_in[11];
  const void* ln2_b  = d_in[12];
  const void* fc1_w  = d_in[13];
  const void* fc1_b  = d_in[14];
  const void* fc2_w  = d_in[15];
  const void* fc2_b  = d_in[16];

  char* ws = (char*)d_ws;
  int* flag  = (int*)(ws + 0);
  u16* fvw   = (u16*)(ws + 256);
  u16* prw   = (u16*)(ws + 590080);
  u16* f1w   = (u16*)(ws + 884992);
  u16* f2w   = (u16*)(ws + 5603584);
  u16* fvb   = (u16*)(ws + 10322176);
  u16* prb   = (u16*)(ws + 10322944);
  u16* f1b   = (u16*)(ws + 10324480);
  u16* f2b_  = (u16*)(ws + 10330624);
  u16* Y1    = (u16*)(ws + 10332416);
  u16* FV    = (u16*)(ws + 35498240);
  u16* Gext  = (u16*)(ws + 48081152);

  // fc1/fc2 chunk rows (multiple of 256 for the 256-tile GEMM).
  const long extra = (long)ws_size - 48081152L;
  u16* G; long crows;
  if (extra >= (long)NTOK * HID_ * 2) { G = Gext; crows = NTOK; }
  else if (extra >= 256L * HID_ * 2) { G = Gext; crows = (extra / (HID_ * 2)) / 256 * 256; }
  else { G = FV; crows = 2048; }  // FV dead after proj; 2048*3072*2 = 12.58 MB fits

  detect_kernel<<<1, 64, 0, stream>>>((const unsigned*)x, flag);

  CvtArgs ca;
  ca.j[0] = {f_w,    fvw,            147456 / 4};
  ca.j[1] = {v_w,    fvw + 147456,   147456 / 4};
  ca.j[2] = {proj_w, prw,            147456 / 4};
  ca.j[3] = {fc1_w,  f1w,            2359296 / 4};
  ca.j[4] = {fc2_w,  f2w,            2359296 / 4};
  ca.j[5] = {f_b,    fvb,            192 / 4};
  ca.j[6] = {v_b,    fvb + 192,      192 / 4};
  ca.j[7] = {proj_b, prb,            768 / 4};
  ca.j[8] = {fc1_b,  f1b,            3072 / 4};
  ca.j[9] = {fc2_b,  f2b_,           768 / 4};
  cvt_kernel<<<dim3(2304, 10), 256, 0, stream>>>(ca, flag);

  // ln1(x) -> Y1 (bf16)
  ln_kernel<<<NTOK, 256, 0, stream>>>(x, ln1_w, ln1_b, Y1, flag);
  // FV = Y1 * [f_w; v_w]^T + [f_b; v_b]   (M=16384, N=384, K=768)
  mfma_gemm<0><<<dim3(128, 3), 256, 0, stream>>>(
      Y1, D_, fvw, D_, fvb, nullptr, FV, 384, D_, 0, flag);
  cluster_kernel<<<128, 512, 0, stream>>>(FV, alpha, beta, flag);
  // h = CL * proj_w^T + proj_b + x -> d_out (flag dtype). A = FV cols [0,192).
  mfma_gemm<2><<<dim3(128, 6), 256, 0, stream>>>(
      FV, 384, prw, INNER_, prb, x, d_out, D_, INNER_, 0, flag);
  // ln2(h) -> Y1 (bf16)
  ln_kernel<<<NTOK, 256, 0, stream>>>(d_out, ln2_w, ln2_b, Y1, flag);
  // fc1 -> G (gelu), fc2 + h residual -> d_out in place, chunked (256-tile)
  for (long t0 = 0; t0 < NTOK; t0 += crows) {
    const long ct = (t0 + crows <= NTOK) ? crows : (NTOK - t0);
    const int gm1 = (int)(ct / 256), gn1 = HID_ / 256;
    const int gm2 = (int)(ct / 256), gn2 = D_ / 256;
    mfma_gemm8<1><<<dim3(gm1 * gn1), 512, 0, stream>>>(
        Y1 + t0 * D_, D_, f1w, D_, f1b, nullptr, G, HID_, D_, 0, gm1, gn1, flag);
    mfma_gemm8<2><<<dim3(gm2 * gn2), 512, 0, stream>>>(
        G, HID_, f2w, HID_, f2b_, d_out, d_out, D_, HID_, (int)t0, gm2, gn2, flag);
  }
}

// Round 4
// 488.057 us; speedup vs baseline: 1.0829x; 1.0705x over previous
//
#include <hip/hip_runtime.h>
#include <hip/hip_bf16.h>
#include <cmath>

typedef unsigned short u16;
typedef short short8 __attribute__((ext_vector_type(8)));   // 8 bf16 (4 VGPRs)
typedef float f32x4 __attribute__((ext_vector_type(4)));    // 4 fp32 acc

#define D_ 768
#define NTOK 16384      // B * N = 16 * 1024
#define INNER_ 192
#define HID_ 3072

__device__ __forceinline__ float u2f(u16 u) { return __uint_as_float((unsigned)u << 16); }
__device__ __forceinline__ u16 f2u(float f) {
  __hip_bfloat16 h = __float2bfloat16(f);
  u16 u; __builtin_memcpy(&u, &h, 2); return u;
}
// Flag-aware scalar load/store: harness tensors are f32 (flag=1) or bf16 (0).
__device__ __forceinline__ float ld1(const void* p, size_t i, int f32) {
  return f32 ? ((const float*)p)[i] : u2f(((const u16*)p)[i]);
}
__device__ __forceinline__ void st1(void* p, size_t i, float v, int f32) {
  if (f32) ((float*)p)[i] = v; else ((u16*)p)[i] = f2u(v);
}
__device__ __forceinline__ float gelu_exact(float v) {
  return 0.5f * v * (1.f + erff(v * 0.7071067811865476f));
}
// Unpack 8 bf16 (uint4) -> 8 f32.
__device__ __forceinline__ void unpack8(const uint4 v, float* o) {
  o[0] = u2f((u16)(v.x & 0xffffu)); o[1] = u2f((u16)(v.x >> 16));
  o[2] = u2f((u16)(v.y & 0xffffu)); o[3] = u2f((u16)(v.y >> 16));
  o[4] = u2f((u16)(v.z & 0xffffu)); o[5] = u2f((u16)(v.z >> 16));
  o[6] = u2f((u16)(v.w & 0xffffu)); o[7] = u2f((u16)(v.w >> 16));
}

// ---------------------------------------------------------------------------
// Dtype detector (verified round 4/5): flag 1 = f32 inputs, 0 = bf16 inputs.
// ---------------------------------------------------------------------------
__global__ __launch_bounds__(64) void detect_kernel(const unsigned* __restrict__ x,
                                                    int* __restrict__ flag) {
  int cnt = 0;
  for (int i = threadIdx.x; i < 512; i += 64) {
    const unsigned e0 = (x[i] >> 7) & 0xFFu;
    if (e0 >= 96u && e0 <= 144u) cnt++;
  }
#pragma unroll
  for (int o = 32; o > 0; o >>= 1) cnt += __shfl_down(cnt, o);
  if (threadIdx.x == 0) flag[0] = (cnt < 256) ? 1 : 0;
}

// ---------------------------------------------------------------------------
// Weight conversion to internal bf16 (10 jobs; grid.y = job id).
// ---------------------------------------------------------------------------
struct CvtJob { const void* src; u16* dst; int n4; };  // n4 = elems/4
struct CvtArgs { CvtJob j[10]; };

__global__ __launch_bounds__(256) void cvt_kernel(CvtArgs a, const int* __restrict__ flagp) {
  const int f32 = flagp[0];
  const CvtJob jb = a.j[blockIdx.y];
  const int i = blockIdx.x * 256 + threadIdx.x;
  if (i >= jb.n4) return;
  if (f32) {
    const float4 v = ((const float4*)jb.src)[i];
    const unsigned lo = (unsigned)f2u(v.x) | ((unsigned)f2u(v.y) << 16);
    const unsigned hi = (unsigned)f2u(v.z) | ((unsigned)f2u(v.w) << 16);
    ((uint2*)jb.dst)[i] = make_uint2(lo, hi);
  } else {
    ((uint2*)jb.dst)[i] = ((const uint2*)jb.src)[i];
  }
}

// ---------------------------------------------------------------------------
// Fused LayerNorm: stats + normalize, one block (256 thr) per token.
// ---------------------------------------------------------------------------
__global__ __launch_bounds__(256) void ln_kernel(const void* __restrict__ x,
                                                 const void* __restrict__ w,
                                                 const void* __restrict__ b,
                                                 u16* __restrict__ y,
                                                 const int* __restrict__ flagp) {
  const int fl = flagp[0];
  const size_t t = blockIdx.x;
  float v[3];
  float s = 0.f, s2 = 0.f;
#pragma unroll
  for (int i = 0; i < 3; i++) {
    v[i] = ld1(x, t * D_ + threadIdx.x + 256 * i, fl);
    s += v[i];
    s2 += v[i] * v[i];
  }
#pragma unroll
  for (int o = 32; o > 0; o >>= 1) {
    s += __shfl_down(s, o);
    s2 += __shfl_down(s2, o);
  }
  __shared__ float ps[4], ps2[4];
  __shared__ float smu, srstd;
  const int wid = threadIdx.x >> 6, lane = threadIdx.x & 63;
  if (lane == 0) { ps[wid] = s; ps2[wid] = s2; }
  __syncthreads();
  if (threadIdx.x == 0) {
    const float a = ps[0] + ps[1] + ps[2] + ps[3];
    const float a2 = ps2[0] + ps2[1] + ps2[2] + ps2[3];
    const float mu = a * (1.f / D_);
    smu = mu;
    srstd = rsqrtf(a2 * (1.f / D_) - mu * mu + 1e-5f);
  }
  __syncthreads();
  const float mu = smu, rstd = srstd;
#pragma unroll
  for (int i = 0; i < 3; i++) {
    const int c = threadIdx.x + 256 * i;
    y[t * D_ + c] = f2u((v[i] - mu) * rstd * ld1(w, c, fl) + ld1(b, c, fl));
  }
}

// ---------------------------------------------------------------------------
// MFMA GEMM (m97 structure, 128x128): kept for fv (N=384) and proj (K=192).
// ---------------------------------------------------------------------------
template <int EPI>
__global__ __launch_bounds__(256) void mfma_gemm(const u16* __restrict__ A, int lda,
                                                 const u16* __restrict__ B, int ldb,
                                                 const u16* __restrict__ bias,
                                                 const void* __restrict__ res,
                                                 void* __restrict__ C, int ldc,
                                                 int K, int row0,
                                                 const int* __restrict__ flagp) {
  const int fl = flagp[0];
  __shared__ __align__(16) u16 Asb[128 * 32];
  __shared__ __align__(16) u16 Bsb[128 * 32];
  const int tid = threadIdx.x;
  const int lane = tid & 63;
  const int wv = tid >> 6;
  const int bm = blockIdx.x * 128;
  const int bn = blockIdx.y * 128;
  const int wm = (wv & 1) * 64;
  const int wn = (wv >> 1) * 64;
  const int c0 = tid, c1 = tid + 256;
  const u16* Ag0 = A + (size_t)(bm + (c0 >> 2)) * lda + (c0 & 3) * 8;
  const u16* Ag1 = A + (size_t)(bm + (c1 >> 2)) * lda + (c1 & 3) * 8;
  const u16* Bg0 = B + (size_t)(bn + (c0 >> 2)) * ldb + (c0 & 3) * 8;
  const u16* Bg1 = B + (size_t)(bn + (c1 >> 2)) * ldb + (c1 & 3) * 8;
  u16* la0 = &Asb[c0 * 8];
  u16* la1 = &Asb[c1 * 8];
  u16* lb0 = &Bsb[c0 * 8];
  u16* lb1 = &Bsb[c1 * 8];

  f32x4 acc[4][4];
#pragma unroll
  for (int i = 0; i < 4; i++)
#pragma unroll
    for (int j = 0; j < 4; j++) acc[i][j] = (f32x4){0.f, 0.f, 0.f, 0.f};

  const int ml = lane & 15;
  const int kq = (lane >> 4) * 8;

  for (int k0 = 0; k0 < K; k0 += 32) {
    __syncthreads();
    __builtin_amdgcn_global_load_lds(
        (const __attribute__((address_space(1))) void*)(Ag0 + k0),
        (__attribute__((address_space(3))) void*)la0, 16, 0, 0);
    __builtin_amdgcn_global_load_lds(
        (const __attribute__((address_space(1))) void*)(Ag1 + k0),
        (__attribute__((address_space(3))) void*)la1, 16, 0, 0);
    __builtin_amdgcn_global_load_lds(
        (const __attribute__((address_space(1))) void*)(Bg0 + k0),
        (__attribute__((address_space(3))) void*)lb0, 16, 0, 0);
    __builtin_amdgcn_global_load_lds(
        (const __attribute__((address_space(1))) void*)(Bg1 + k0),
        (__attribute__((address_space(3))) void*)lb1, 16, 0, 0);
    __syncthreads();
    short8 af[4], bf[4];
#pragma unroll
    for (int i = 0; i < 4; i++) {
      af[i] = *(const short8*)&Asb[(wm + i * 16 + ml) * 32 + kq];
      bf[i] = *(const short8*)&Bsb[(wn + i * 16 + ml) * 32 + kq];
    }
#pragma unroll
    for (int i = 0; i < 4; i++)
#pragma unroll
      for (int j = 0; j < 4; j++)
        acc[i][j] = __builtin_amdgcn_mfma_f32_16x16x32_bf16(af[i], bf[j], acc[i][j], 0, 0, 0);
  }

  const int qr = (lane >> 4) * 4;
#pragma unroll
  for (int i = 0; i < 4; i++) {
#pragma unroll
    for (int j = 0; j < 4; j++) {
      const int colg = bn + wn + j * 16 + ml;
      const float bb = u2f(bias[colg]);
#pragma unroll
      for (int r = 0; r < 4; r++) {
        const size_t row = (size_t)row0 + bm + wm + i * 16 + qr + r;
        float v = acc[i][j][r] + bb;
        if (EPI == 1) v = gelu_exact(v);
        if (EPI == 2) {
          v += ld1(res, row * ldc + colg, fl);
          st1(C, row * ldc + colg, v, fl);
        } else {
          ((u16*)C)[row * ldc + colg] = f2u(v);
        }
      }
    }
  }
}

// ---------------------------------------------------------------------------
// mfma_gemmP: 128x256 tile, BK=32, 8 waves (wave = 64x64, acc[4][4] = 64 VGPR),
// __launch_bounds__(512,4) => <=128 VGPR => 2 blocks/CU (16 waves/CU).
// Round-3 evidence: the 256^2 8-wave tile is VGPR-capped at 1 block/CU and
// under-demands (4.5 TB/s delivered); round-0's 128^2 kernel at 2-3 blocks/CU
// demanded 6-7.8 TB/s via cross-block overlap (m114) + L1 panel sharing.
// This tile keeps 256^2-level external-bytes/FLOP via pairing while restoring
// 2 blocks/CU.
// LDS: TRIPLE buffer [3][(128+256)*32] bf16 = 72 KB (2 blocks = 144 <= 160).
// Triple-buffering makes the in-phase stage of tile t+2 write-safe: it targets
// buf (t+2)%3 = buf (t-1)%3, whose last reads finished before phase t-1's end
// barrier. One phase per tile: {8 ds_read_b128; stage t+2 (3 gl_lds);
// vmcnt(3) counted; barrier; lgkmcnt(0)+sched_barrier; setprio; 16 MFMA;
// setprio; barrier}. vmcnt(3): in-flight = stage(t+1) 3 + stage(t+2) 3;
// wait drains t+1 exactly. XOR swizzle both-sides as in round 2 (0 conflicts).
// Grid map (1D, ntot = gm*gn blocks):
//   mode 1 (ntot%512==0 && 512%gm==0 && gm>=2): layer l=bid>>8, p=bid&255,
//     G=gm/2: bn = (l>>1)*(512/gm) + p/G; mb = (p%G)*2 + (l&1). Bijective;
//     co-resident pairs (bid, bid+256) AND (2k, 2k+1) share the B-panel.
//   mode 0: mb = bid%gm, bn = bid/gm (gm=128 | 256 => layer pairs share A).
// K accumulation order identical (k = 0,32,64,... linear) => bit-identical.
// Requires M%128==0, N%256==0, K%32==0.
// ---------------------------------------------------------------------------
#define SB8 __builtin_amdgcn_sched_barrier(0)
#define BAR8 __builtin_amdgcn_s_barrier()

template <int EPI>
__global__ __launch_bounds__(512, 4) void mfma_gemmP(const u16* __restrict__ A, int lda,
                                                     const u16* __restrict__ B, int ldb,
                                                     const u16* __restrict__ bias,
                                                     const void* __restrict__ res,
                                                     void* __restrict__ C, int ldc,
                                                     int K, int row0, int gm, int gn,
                                                     const int* __restrict__ flagp) {
  const int fl = flagp[0];
  __shared__ __align__(16) u16 L[3][(128 + 256) * 32];  // A @0 (4096), B @4096 (8192)
  const int tid = threadIdx.x;
  const int lane = tid & 63;
  const int wv = tid >> 6;

  // ---- block remap
  int mb_, nb_;
  {
    const int bid = blockIdx.x;
    const int ntot = gm * gn;
    if ((ntot & 511) == 0 && (512 % gm) == 0 && gm >= 2) {
      const int l = bid >> 8, p = bid & 255;
      const int G = gm >> 1;
      nb_ = (l >> 1) * (512 / gm) + p / G;
      mb_ = (p % G) * 2 + (l & 1);
    } else {
      mb_ = bid % gm;
      nb_ = bid / gm;
    }
  }
  const int bm = mb_ * 128;
  const int bn = nb_ * 256;

  const int wm = (wv & 1) * 64;
  const int wn = (wv >> 1) * 64;
  const int ml = lane & 15;
  const int qk = lane >> 4;        // 16B chunk within k-slice

  // Staging geometry: row = tid>>2 (0..127), slot = tid&3,
  // global chunk q = slot ^ ((row>>1)&3)  (same q for row and row+128).
  const int srow = tid >> 2;
  const int q_s = (tid & 3) ^ ((srow >> 1) & 3);
  const size_t gaA  = (size_t)(bm + srow) * lda + q_s * 8;
  const size_t gbB0 = (size_t)(bn + srow) * ldb + q_s * 8;
  const size_t gbB1 = (size_t)(bn + srow + 128) * ldb + q_s * 8;

  // LDS read offsets (elems), swizzled. A rows wm+i*16+ml; B rows wn+j*16+ml.
  int offA[4], offB[4];
#pragma unroll
  for (int i = 0; i < 4; i++) {
    const int r = wm + i * 16 + ml;
    offA[i] = (r * 4 + (qk ^ ((r >> 1) & 3))) * 8;
  }
#pragma unroll
  for (int j = 0; j < 4; j++) {
    const int r = wn + j * 16 + ml;
    offB[j] = 4096 + (r * 4 + (qk ^ ((r >> 1) & 3))) * 8;
  }

  f32x4 acc[4][4];
#pragma unroll
  for (int i = 0; i < 4; i++)
#pragma unroll
    for (int j = 0; j < 4; j++) acc[i][j] = (f32x4){0.f, 0.f, 0.f, 0.f};

  const int NT = K >> 5;

#define STGP(tilex) do {                                                            \
    const size_t k_ = (size_t)(tilex) * 32;                                         \
    u16* lb_ = &L[(tilex) % 3][0];                                                  \
    __builtin_amdgcn_global_load_lds(                                               \
        (const __attribute__((address_space(1))) void*)(A + gaA + k_),              \
        (__attribute__((address_space(3))) void*)(lb_ + tid * 8), 16, 0, 0);        \
    __builtin_amdgcn_global_load_lds(                                               \
        (const __attribute__((address_space(1))) void*)(B + gbB0 + k_),             \
        (__attribute__((address_space(3))) void*)(lb_ + 4096 + tid * 8), 16, 0, 0); \
    __builtin_amdgcn_global_load_lds(                                               \
        (const __attribute__((address_space(1))) void*)(B + gbB1 + k_),             \
        (__attribute__((address_space(3))) void*)(lb_ + 4096 + (tid + 512) * 8), 16, 0, 0); \
  } while (0)

  // Prologue
  STGP(0);
  if (NT > 1) {
    STGP(1);
    asm volatile("s_waitcnt vmcnt(3)" ::: "memory");   // tile 0 landed
  } else {
    asm volatile("s_waitcnt vmcnt(0)" ::: "memory");
  }
  SB8; BAR8; SB8;

  for (int t = 0; t < NT; t++) {
    const u16* Lb = &L[t % 3][0];
    short8 af[4], bf[4];
#pragma unroll
    for (int j = 0; j < 4; j++) bf[j] = *(const short8*)(Lb + offB[j]);
#pragma unroll
    for (int i = 0; i < 4; i++) af[i] = *(const short8*)(Lb + offA[i]);
    if (t + 2 < NT) {
      STGP(t + 2);
      asm volatile("s_waitcnt vmcnt(3)" ::: "memory"); // tile t+1 landed
    } else if (t + 1 < NT) {
      asm volatile("s_waitcnt vmcnt(0)" ::: "memory"); // drain last tile
    }
    SB8; BAR8;
    asm volatile("s_waitcnt lgkmcnt(0)" ::: "memory"); SB8;
    __builtin_amdgcn_s_setprio(1);
#pragma unroll
    for (int i = 0; i < 4; i++)
#pragma unroll
      for (int j = 0; j < 4; j++)
        acc[i][j] = __builtin_amdgcn_mfma_f32_16x16x32_bf16(af[i], bf[j], acc[i][j], 0, 0, 0);
    __builtin_amdgcn_s_setprio(0);
    SB8; BAR8;
  }
#undef STGP

  // Epilogue. C/D layout: col = lane&15, row = (lane>>4)*4 + reg.
  const int qr = (lane >> 4) * 4;
#pragma unroll
  for (int i = 0; i < 4; i++) {
#pragma unroll
    for (int j = 0; j < 4; j++) {
      const int colg = bn + wn + j * 16 + ml;
      const float bb = u2f(bias[colg]);
#pragma unroll
      for (int r = 0; r < 4; r++) {
        const size_t row = (size_t)row0 + bm + wm + i * 16 + qr + r;
        float v = acc[i][j][r] + bb;
        if (EPI == 1) v = gelu_exact(v);
        if (EPI == 2) {
          v += ld1(res, row * ldc + colg, fl);
          st1(C, row * ldc + colg, v, fl);
        } else {
          ((u16*)C)[row * ldc + colg] = f2u(v);
        }
      }
    }
  }
}

// ---------------------------------------------------------------------------
// Cluster kernel (round-6 structure; unchanged this round).
// ---------------------------------------------------------------------------
__global__ __launch_bounds__(512) void cluster_kernel(u16* __restrict__ FV,
                                                      const void* __restrict__ alpha_p,
                                                      const void* __restrict__ beta_p,
                                                      const int* __restrict__ flagp) {
  const int fl = flagp[0];
  const int be = blockIdx.x;       // 0..127
  const int b = be >> 3, e = be & 7;
  const int tid = threadIdx.x;
  const float alpha = ld1(alpha_p, 0, fl), beta = ld1(beta_p, 0, fl);

  __shared__ __align__(16) u16 S[1024 * 24];   // staged F, then V (48 KB)
  __shared__ float cn[16][24];
  __shared__ float vcen[16][24];
  __shared__ float outc[16][24];
  __shared__ float rcn[16];
  __shared__ int cnt[16];

  u16* Fg = FV + ((size_t)b * 1024) * 384 + e * 24;
  const u16* Vg = Fg + 192;

  for (int c = tid; c < 3072; c += 512) {
    const int n = c / 3, q = c - n * 3;
    *(uint4*)&S[n * 24 + q * 8] = *(const uint4*)(Fg + (size_t)n * 384 + q * 8);
  }
  if (tid < 16) cnt[tid] = 0;
  __syncthreads();

  for (int t = tid; t < 384; t += 512) {
    const int m = t / 24, ch = t - m * 24;
    const int pw = m >> 2, ph = m & 3;
    float sum = 0.f;
    for (int dw = 0; dw < 8; dw++) {
      const int base = (pw * 8 + dw) * 32 + ph * 8;
      for (int dh = 0; dh < 8; dh++) sum += u2f(S[(base + dh) * 24 + ch]);
    }
    cn[m][ch] = sum * (1.f / 64.f);
  }
  __syncthreads();
  if (tid < 16) {
    float s = 0.f;
    for (int ch = 0; ch < 24; ch++) { const float v = cn[tid][ch]; s += v * v; }
    rcn[tid] = 1.f / fmaxf(sqrtf(s), 1e-12f);
  }
  __syncthreads();

  const int na = tid, nb = tid + 512;
  float besta = -3.4e38f, bestb = -3.4e38f;
  int bma = 0, bmb = 0;
  {
    float xa[24], xb[24];
    const uint4* ra = (const uint4*)&S[na * 24];
    const uint4* rb = (const uint4*)&S[nb * 24];
#pragma unroll
    for (int q = 0; q < 3; q++) {
      unpack8(ra[q], &xa[q * 8]);
      unpack8(rb[q], &xb[q * 8]);
    }
    float ssa = 0.f, ssb = 0.f;
#pragma unroll
    for (int ch = 0; ch < 24; ch++) {
      ssa = fmaf(xa[ch], xa[ch], ssa);
      ssb = fmaf(xb[ch], xb[ch], ssb);
    }
    const float rna = 1.f / fmaxf(sqrtf(ssa), 1e-12f);
    const float rnb = 1.f / fmaxf(sqrtf(ssb), 1e-12f);
    for (int m = 0; m < 16; m++) {
      float da = 0.f, db = 0.f;
#pragma unroll
      for (int k = 0; k < 12; k++) {
        const float2 c = *(const float2*)&cn[m][2 * k];
        da = fmaf(c.x, xa[2 * k], da); da = fmaf(c.y, xa[2 * k + 1], da);
        db = fmaf(c.x, xb[2 * k], db); db = fmaf(c.y, xb[2 * k + 1], db);
      }
      const float rc = rcn[m];
      da *= rna * rc;
      db *= rnb * rc;
      const float dda = sqrtf(fmaxf(2.f - 2.f * da, 1e-12f));
      const float ddb = sqrtf(fmaxf(2.f - 2.f * db, 1e-12f));
      const float za = beta + alpha * expf(-dda);
      const float zb = beta + alpha * expf(-ddb);
      const float sa = (za >= 0.f) ? za : 0.2f * za;
      const float sb = (zb >= 0.f) ? zb : 0.2f * zb;
      if (sa > besta) { besta = sa; bma = m; }
      if (sb > bestb) { bestb = sb; bmb = m; }
    }
    atomicAdd(&cnt[bma], 1);
    atomicAdd(&cnt[bmb], 1);
  }
  __syncthreads();

  for (int c = tid; c < 3072; c += 512) {
    const int n = c / 3, q = c - n * 3;
    *(uint4*)&S[n * 24 + q * 8] = *(const uint4*)(Vg + (size_t)n * 384 + q * 8);
  }
  if (tid < 384) outc[tid / 24][tid - (tid / 24) * 24] = 0.f;
  __syncthreads();

  for (int t = tid; t < 384; t += 512) {
    const int m = t / 24, ch = t - m * 24;
    const int pw = m >> 2, ph = m & 3;
    float sum = 0.f;
    for (int dw = 0; dw < 8; dw++) {
      const int base = (pw * 8 + dw) * 32 + ph * 8;
      for (int dh = 0; dh < 8; dh++) sum += u2f(S[(base + dh) * 24 + ch]);
    }
    vcen[m][ch] = sum * (1.f / 64.f);
  }

  {
    float va[24], vb[24];
    const uint4* ra = (const uint4*)&S[na * 24];
    const uint4* rb = (const uint4*)&S[nb * 24];
#pragma unroll
    for (int q = 0; q < 3; q++) {
      unpack8(ra[q], &va[q * 8]);
      unpack8(rb[q], &vb[q * 8]);
    }
#pragma unroll
    for (int ch = 0; ch < 24; ch++) {
      atomicAdd(&outc[bma][ch], besta * va[ch]);
      atomicAdd(&outc[bmb][ch], bestb * vb[ch]);
    }
  }
  __syncthreads();

  for (int t = tid; t < 384; t += 512) {
    const int m = t / 24, ch = t - m * 24;
    outc[m][ch] = (outc[m][ch] + vcen[m][ch]) / ((float)cnt[m] + 1.f);
  }
  __syncthreads();

#pragma unroll
  for (int pass = 0; pass < 2; pass++) {
    const int n = pass ? nb : na;
    const int m = pass ? bmb : bma;
    const float s = pass ? bestb : besta;
    unsigned w[12];
#pragma unroll
    for (int k = 0; k < 12; k++) {
      w[k] = (unsigned)f2u(s * outc[m][2 * k]) |
             ((unsigned)f2u(s * outc[m][2 * k + 1]) << 16);
    }
    uint4* dst = (uint4*)(Fg + (size_t)n * 384);
    dst[0] = make_uint4(w[0], w[1], w[2], w[3]);
    dst[1] = make_uint4(w[4], w[5], w[6], w[7]);
    dst[2] = make_uint4(w[8], w[9], w[10], w[11]);
  }
}

// ---------------------------------------------------------------------------
// Workspace layout (floor 48.1 MB; G beyond that, adaptive):
//   flag @0 | fv_w @256 | proj_w @590080 | fc1_w @884992 | fc2_w @5603584
//   fvb @10322176 | projb @10322944 | fc1b @10324480 | fc2b @10330624
//   Y1 bf16 16384x768 @10332416 | FV bf16 16384x384 @35498240 | G @48081152
// ---------------------------------------------------------------------------
extern "C" void kernel_launch(void* const* d_in, const int* in_sizes, int n_in,
                              void* d_out, int out_size, void* d_ws, size_t ws_size,
                              hipStream_t stream) {
  const void* x      = d_in[0];
  const void* ln1_w  = d_in[1];
  const void* ln1_b  = d_in[2];
  const void* f_w    = d_in[3];
  const void* f_b    = d_in[4];
  const void* v_w    = d_in[5];
  const void* v_b    = d_in[6];
  const void* proj_w = d_in[7];
  const void* proj_b = d_in[8];
  const void* alpha  = d_in[9];
  const void* beta   = d_in[10];
  const void* ln2_w  = d_in[11];
  const void* ln2_b  = d_in[12];
  const void* fc1_w  = d_in[13];
  const void* fc1_b  = d_in[14];
  const void* fc2_w  = d_in[15];
  const void* fc2_b  = d_in[16];

  char* ws = (char*)d_ws;
  int* flag  = (int*)(ws + 0);
  u16* fvw   = (u16*)(ws + 256);
  u16* prw   = (u16*)(ws + 590080);
  u16* f1w   = (u16*)(ws + 884992);
  u16* f2w   = (u16*)(ws + 5603584);
  u16* fvb   = (u16*)(ws + 10322176);
  u16* prb   = (u16*)(ws + 10322944);
  u16* f1b   = (u16*)(ws + 10324480);
  u16* f2b_  = (u16*)(ws + 10330624);
  u16* Y1    = (u16*)(ws + 10332416);
  u16* FV    = (u16*)(ws + 35498240);
  u16* Gext  = (u16*)(ws + 48081152);

  // fc1/fc2 chunk rows (multiple of 256), pure function of ws_size.
  const long extra = (long)ws_size - 48081152L;
  u16* G; long crows;
  if (extra >= (long)NTOK * HID_ * 2) { G = Gext; crows = NTOK; }
  else if (extra >= 256L * HID_ * 2) { G = Gext; crows = (extra / (HID_ * 2)) / 256 * 256; }
  else { G = FV; crows = 2048; }  // FV dead after proj; 2048*3072*2 = 12.58 MB fits

  detect_kernel<<<1, 64, 0, stream>>>((const unsigned*)x, flag);

  CvtArgs ca;
  ca.j[0] = {f_w,    fvw,            147456 / 4};
  ca.j[1] = {v_w,    fvw + 147456,   147456 / 4};
  ca.j[2] = {proj_w, prw,            147456 / 4};
  ca.j[3] = {fc1_w,  f1w,            2359296 / 4};
  ca.j[4] = {fc2_w,  f2w,            2359296 / 4};
  ca.j[5] = {f_b,    fvb,            192 / 4};
  ca.j[6] = {v_b,    fvb + 192,      192 / 4};
  ca.j[7] = {proj_b, prb,            768 / 4};
  ca.j[8] = {fc1_b,  f1b,            3072 / 4};
  ca.j[9] = {fc2_b,  f2b_,           768 / 4};
  cvt_kernel<<<dim3(2304, 10), 256, 0, stream>>>(ca, flag);

  // ln1(x) -> Y1 (bf16)
  ln_kernel<<<NTOK, 256, 0, stream>>>(x, ln1_w, ln1_b, Y1, flag);
  // FV = Y1 * [f_w; v_w]^T + [f_b; v_b]   (M=16384, N=384, K=768)
  mfma_gemm<0><<<dim3(128, 3), 256, 0, stream>>>(
      Y1, D_, fvw, D_, fvb, nullptr, FV, 384, D_, 0, flag);
  cluster_kernel<<<128, 512, 0, stream>>>(FV, alpha, beta, flag);
  // h = CL * proj_w^T + proj_b + x -> d_out (flag dtype). A = FV cols [0,192).
  mfma_gemm<2><<<dim3(128, 6), 256, 0, stream>>>(
      FV, 384, prw, INNER_, prb, x, d_out, D_, INNER_, 0, flag);
  // ln2(h) -> Y1 (bf16)
  ln_kernel<<<NTOK, 256, 0, stream>>>(d_out, ln2_w, ln2_b, Y1, flag);
  // fc1 -> G (gelu), fc2 + h residual -> d_out in place, chunked (128x256 tile)
  for (long t0 = 0; t0 < NTOK; t0 += crows) {
    const long ct = (t0 + crows <= NTOK) ? crows : (NTOK - t0);
    const int gm1 = (int)(ct / 128), gn1 = HID_ / 256;
    const int gm2 = (int)(ct / 128), gn2 = D_ / 256;
    mfma_gemmP<1><<<dim3(gm1 * gn1), 512, 0, stream>>>(
        Y1 + t0 * D_, D_, f1w, D_, f1b, nullptr, G, HID_, D_, 0, gm1, gn1, flag);
    mfma_gemmP<2><<<dim3(gm2 * gn2), 512, 0, stream>>>(
        G, HID_, f2w, HID_, f2b_, d_out, d_out, D_, HID_, (int)t0, gm2, gn2, flag);
  }
}